// Round 11
// baseline (172.659 us; speedup 1.0000x reference)
//
#include <hip/hip_runtime.h>
#include <math.h>

#define B_TOTAL 32768
#define TB 64
#define NCH 256
#define EPS 1e-5f

typedef unsigned short u16;
typedef __attribute__((ext_vector_type(8))) short short8;
typedef __attribute__((ext_vector_type(4))) float f32x4;

__device__ __forceinline__ u16 f2bf(float f) {  // RNE
  unsigned int u = __builtin_bit_cast(unsigned int, f);
  u = (u + 0x7fffu + ((u >> 16) & 1u)) >> 16;
  return (u16)u;
}
__device__ __forceinline__ short8 u4s8(uint4 v) {
  return __builtin_bit_cast(short8, v);
}

// ---------------------------------------------------------------------------
// prep (257 blocks):
//   0..127   stats: 256 boards each (2 passes), atomicAdd into sums; 128th
//            finisher computes BN-affine A,D inline (T-matrix reduction).
//   128..255 pack [pw1|vw1] -> Wp (bf16 B-fragment order), 384 chunks each.
//   256      pack [pw2|vw2] -> Wp2 (512 chunks) and convw -> Wc conv
//            A-fragments (1024 chunks, zeros for lq>=2).
// ---------------------------------------------------------------------------
__global__ __launch_bounds__(256) void prep_kernel(
    const float* __restrict__ x, const float* __restrict__ pw1,
    const float* __restrict__ vw1, const float* __restrict__ pw2,
    const float* __restrict__ vw2, const float* __restrict__ convw,
    const float* __restrict__ convb, const float* __restrict__ gamma,
    const float* __restrict__ beta, u16* __restrict__ Wp,
    u16* __restrict__ Wp2, u16* __restrict__ Wc, float* __restrict__ sums,
    int* __restrict__ ctr, float* __restrict__ AD) {
  const int tid = threadIdx.x;
  if (blockIdx.x == 256) {
    // ---- W2 pack: chunk id = ((h*2+k2)*2+t)*64 + lq*16 + lm ----
#pragma unroll
    for (int k = 0; k < 2; ++k) {
      const int id = k * 256 + tid;  // < 512
      const int lm = id & 15, lq = (id >> 4) & 3, t = (id >> 6) & 1;
      const int k2 = (id >> 7) & 1, h = (id >> 8) & 1;
      const float* w2 = h ? vw2 : pw2;
      union { u16 s[8]; uint4 v; } pk;
#pragma unroll
      for (int j = 0; j < 8; ++j)
        pk.s[j] = f2bf(w2[(k2 * 32 + lq * 8 + j) * 32 + t * 16 + lm]);
      *(uint4*)&Wp2[(size_t)id * 8] = pk.v;
    }
    // ---- Wc pack: chunk id = gp*64 + lq*16 + lm (lane-linear per gp) ----
#pragma unroll
    for (int k = 0; k < 4; ++k) {
      const int c = k * 256 + tid;  // < 1024
      const int lm = c & 15, lq = (c >> 4) & 3, gp = c >> 6;
      const int chan = gp * 16 + lm;
      union { u16 s[8]; uint4 v; } pk;
      if (lq < 2) {
#pragma unroll
        for (int j = 0; j < 8; ++j)
          pk.s[j] = f2bf(convw[chan * 16 + lq * 8 + j]);
      } else {
#pragma unroll
        for (int j = 0; j < 8; ++j) pk.s[j] = 0;
      }
      *(uint4*)&Wc[(size_t)c * 8] = pk.v;
    }
    return;
  }
  if (blockIdx.x >= 128) {
    const int base = (blockIdx.x - 128) * 384;
#pragma unroll
    for (int k = 0; k < 2; ++k) {
      const int s = k * 256 + tid;
      if (s >= 384) break;
      const int id = base + s;  // < 49152
      const int g = id / 1536;
      const int rem = id - g * 1536;
      const int kt = rem >> 9;
      const int ctl = (rem >> 6) & 7;
      const int lq = (rem >> 4) & 3;
      const int lm = rem & 15;
      const int p = kt * 4 + lq;
      const int col = ctl * 16 + lm;
      union { u16 s[8]; uint4 v; } pk;
#pragma unroll
      for (int j = 0; j < 8; ++j) {
        int r = (g * 8 + j) * 12 + p;
        float w = (col < 64) ? pw1[r * 64 + col] : vw1[r * 64 + (col - 64)];
        pk.s[j] = f2bf(w);
      }
      *(uint4*)&Wp[(size_t)id * 8] = pk.v;
    }
    return;
  }
  // ---- stats branch: 256 boards over 2 passes of 128 ----
  __shared__ float xb[128 * 44];
  __shared__ int elect;
  const int bid = blockIdx.x;
  if (tid < 128) { xb[tid * 44 + 42] = 0.f; xb[tid * 44 + 43] = 0.f; }
  const int ti = tid / 22, tj = tid - (tid / 22) * 22;  // 11 x 22 = 242
  const int i0 = ti * 4, j0 = tj * 2;
  float acc[4][2];
#pragma unroll
  for (int i = 0; i < 4; ++i) { acc[i][0] = 0.f; acc[i][1] = 0.f; }
  float msum = 0.f;
  for (int pass = 0; pass < 2; ++pass) {
    if (pass) __syncthreads();
    const float4* src =
        (const float4*)(x + (size_t)(bid * 2 + pass) * 128 * 42);
    for (int i = tid; i < 1344; i += 256) {
      float4 v = src[i];
      float vals[4] = {v.x, v.y, v.z, v.w};
#pragma unroll
      for (int e = 0; e < 4; ++e) {
        int idx = i * 4 + e;
        int b = idx / 42;
        int pos = idx - b * 42;
        xb[b * 44 + pos] = vals[e];
      }
    }
    __syncthreads();
    if (tid < 242) {
      for (int b = 0; b < 128; ++b) {
        f32x4 va = *(const f32x4*)&xb[b * 44 + i0];
        float2 vb = *(const float2*)&xb[b * 44 + j0];
#pragma unroll
        for (int i = 0; i < 4; ++i) {
          acc[i][0] = fmaf(va[i], vb.x, acc[i][0]);
          acc[i][1] = fmaf(va[i], vb.y, acc[i][1]);
        }
      }
    }
    if (tid < 42) {
      float a = 0.f;
      for (int b = 0; b < 128; ++b) a += xb[b * 44 + tid];
      msum += a;
    }
  }
  if (tid < 242) {
#pragma unroll
    for (int i = 0; i < 4; ++i)
#pragma unroll
      for (int j = 0; j < 2; ++j) {
        int gi = i0 + i, gj = j0 + j;
        if (gi < 42 && gj < 42) atomicAdd(&sums[42 + gi * 42 + gj], acc[i][j]);
      }
  }
  if (tid < 42) atomicAdd(&sums[tid], msum);
  __threadfence();
  __syncthreads();
  if (tid == 0) {
    int old = __hip_atomic_fetch_add(ctr, 1, __ATOMIC_ACQ_REL,
                                     __HIP_MEMORY_SCOPE_AGENT);
    elect = (old == 127);
  }
  __syncthreads();
  if (!elect) return;

  // ---- inline stats2 (only the 128th-finishing block) ----
  float* sM = xb;           // 42
  float* sS = xb + 42;      // 42*42
  float* T = xb + 1806;     // 16*16
  float* M16 = xb + 2062;   // 16
  const float invB = 1.f / (float)B_TOTAL;
  for (int idx = tid; idx < 1806; idx += 256) {
    float v = __hip_atomic_load(&sums[idx], __ATOMIC_RELAXED,
                                __HIP_MEMORY_SCOPE_AGENT) * invB;
    if (idx < 42) sM[idx] = v; else sS[idx - 42] = v;
  }
  __syncthreads();
  {
    const int k = tid >> 4, k2 = tid & 15;
    float s = 0.f;
#pragma unroll
    for (int p = 0; p < 12; ++p) {
      int pi = p >> 2, pj = p & 3;
      int i1 = (pi + (k >> 2)) * 7 + pj + (k & 3);
      int i2 = (pi + (k2 >> 2)) * 7 + pj + (k2 & 3);
      s += sS[i1 * 42 + i2];
    }
    T[tid] = s;
    if (tid < 16) {
      float m = 0.f;
#pragma unroll
      for (int p = 0; p < 12; ++p) {
        int pi = p >> 2, pj = p & 3;
        m += sM[(pi + (tid >> 2)) * 7 + pj + (tid & 3)];
      }
      M16[tid] = m;
    }
  }
  __syncthreads();
  {
    float w[16];
#pragma unroll
    for (int k = 0; k < 16; ++k) w[k] = convw[tid * 16 + k];
    const float cb = convb[tid];
    float accm = 0.f, q = 0.f;
#pragma unroll
    for (int k = 0; k < 16; ++k) {
      accm = fmaf(w[k], M16[k], accm);
      float t = 0.f;
#pragma unroll
      for (int k2 = 0; k2 < 16; ++k2) t = fmaf(w[k2], T[k * 16 + k2], t);
      q = fmaf(w[k], t, q);
    }
    const float meanY = cb + accm * (1.f / 12.f);
    const float EY2 = cb * cb + (2.f * cb * accm + q) * (1.f / 12.f);
    float var = EY2 - meanY * meanY;
    var = fmaxf(var, 0.f);
    const float alpha = gamma[tid] * rsqrtf(var + EPS);
    AD[tid] = alpha;
    AD[NCH + tid] = beta[tid] + alpha * (cb - meanY);
  }
}

// ---------------------------------------------------------------------------
// fused — R9 base (proven) + Wc conv-weight fragments + Wp2 layer-2 (F,
// exonerated). Serial layer-3 (G convicted & dropped).
// ---------------------------------------------------------------------------
struct S1 {
  float ADs[512];                                            // 2048 B
  union { u16 Bpatch[12288]; u16 Apk0[12288]; } a;           // 24576 B
  union { float boards[TB * 43]; u16 Apk1[12288]; } b;       // 24576 B
};
struct S2 {
  float act[TB * 132];
  float p2v2[TB * 65];
};
union Sh { S1 s1; S2 s2; };

__global__ __launch_bounds__(256, 3) void fused_kernel(
    const float* __restrict__ x, const u16* __restrict__ Wc,
    const float* __restrict__ AD, const u16* __restrict__ Wp,
    const u16* __restrict__ Wp2,
    const float* __restrict__ pb1, const float* __restrict__ vb1,
    const float* __restrict__ pb2, const float* __restrict__ pw3,
    const float* __restrict__ pb3, const float* __restrict__ vb2,
    const float* __restrict__ vw3, const float* __restrict__ vb3,
    float* __restrict__ out) {
  __shared__ Sh sh;
  const int tid = threadIdx.x;
  const int bid = blockIdx.x;
  const int l = tid & 63, wv = tid >> 6;
  const int lm = l & 15, lq = l >> 4;
  const uint4* Wp4 = (const uint4*)Wp;
  const uint4* Wc4 = (const uint4*)Wc;

  // stage boards into padded LDS (region later reused as Apk1)
  {
    const float4* src = (const float4*)(x + (size_t)bid * (TB * 42));
    for (int i = tid; i < (TB * 42) / 4; i += 256) {
      float4 v = src[i];
      float vals[4] = {v.x, v.y, v.z, v.w};
#pragma unroll
      for (int e = 0; e < 4; ++e) {
        int idx = i * 4 + e;
        int b = idx / 42;
        int pos = idx - b * 42;
        sh.s1.b.boards[b * 43 + pos] = vals[e];
      }
    }
  }
  sh.s1.ADs[tid] = AD[tid];
  sh.s1.ADs[256 + tid] = AD[256 + tid];
  __syncthreads();

  // build conv patch B-fragments in LDS (once)
#pragma unroll
  for (int i = 0; i < 6; ++i) {
    int s = i * 256 + tid;
    int plm = s & 15, lq2 = (s >> 4) & 1, nt = s >> 5;
    int p = nt >> 2, b = ((nt & 3) << 4) | plm;
    int pi = p >> 2, pj = p & 3;
    const float* bd = &sh.s1.b.boards[b * 43 + (pi + lq2 * 2) * 7 + pj];
    union { u16 s8[8]; uint4 q; } pk;
#pragma unroll
    for (int d = 0; d < 4; ++d) {
      pk.s8[d] = f2bf(bd[d]);
      pk.s8[4 + d] = f2bf(bd[7 + d]);
    }
    *(uint4*)&sh.s1.a.Bpatch[(size_t)((nt * 2 + lq2) * 16 + plm) * 8] = pk.q;
  }
  __syncthreads();  // Bpatch ready; boards consumed

  // patch fragments -> registers (gp-invariant). lq>=2 duplicates lq&1 rows
  // (finite data; multiplied by zero A-weights baked into Wc).
  uint4 bp[12];
#pragma unroll
  for (int i = 0; i < 12; ++i) {
    int nt = i * 4 + wv;
    bp[i] = *(const uint4*)&sh.s1.a.Bpatch[(size_t)((nt * 2 + (lq & 1)) * 16 + lm) * 8];
  }
  __syncthreads();  // all bp reads done; Apk0 (=Bpatch) region free

  f32x4 acc[4][2];
#pragma unroll
  for (int R = 0; R < 4; ++R)
#pragma unroll
    for (int t = 0; t < 2; ++t)
#pragma unroll
      for (int r = 0; r < 4; ++r) acc[R][t][r] = 0.f;

  const int parw = lq >> 1, hw = lq & 1;
  char* const apk0 = (char*)sh.s1.a.Apk0;
  char* const apk1 = (char*)sh.s1.b.Apk1;

  // conv for group-pair gp into buffer: 16 channels, K=16 live of K=32;
  // weight A-fragment comes pre-packed (awv_, one dwordx4 from Wc).
#define CONV_STEP(gp_, wbuf_, awv_)                                            \
  {                                                                            \
    const f32x4 A4 = *(const f32x4*)&sh.s1.ADs[(gp_)*16 + lq * 4];             \
    const f32x4 D4 = *(const f32x4*)&sh.s1.ADs[256 + (gp_)*16 + lq * 4];       \
    _Pragma("unroll") for (int i = 0; i < 12; ++i) {                           \
      const int nt = i * 4 + wv;                                               \
      f32x4 c = {0.f, 0.f, 0.f, 0.f};                                          \
      c = __builtin_amdgcn_mfma_f32_16x16x32_bf16(u4s8(awv_), u4s8(bp[i]), c,  \
                                                  0, 0, 0);                    \
      union { u16 s4[4]; uint2 q; } hp;                                        \
      _Pragma("unroll") for (int r = 0; r < 4; ++r) hp.s4[r] =                 \
          f2bf(fmaxf(fmaf(c[r], A4[r], D4[r]), 0.f));                          \
      const int K_ = nt >> 4, kq_ = (nt >> 2) & 3, R_ = nt & 3;                \
      const int off = ((parw * 3 + K_) * 4 + R_) * 1024 +                      \
                      (kq_ * 16 + lm) * 16 + hw * 8;                           \
      *(uint2*)((wbuf_) + off) = hp.q;                                         \
    }                                                                          \
  }

  {
    uint4 aw0 = Wc4[0 * 64 + l];
    CONV_STEP(0, apk0, aw0);
  }

#pragma unroll 1
  for (int gp = 0; gp < 16; ++gp) {
    __syncthreads();  // Apk[gp&1] written; prev GEMM done with Apk[(gp+1)&1]

    // B fragments for this gp from L2 (lane-linear, coalesced) + next aw
    uint4 Bv[12];
#pragma unroll
    for (int par = 0; par < 2; ++par)
#pragma unroll
      for (int K = 0; K < 3; ++K)
#pragma unroll
        for (int t = 0; t < 2; ++t)
          Bv[par * 6 + K * 2 + t] =
              Wp4[(size_t)(2 * gp + par) * 1536 + K * 512 + (wv * 2 + t) * 64 + l];
    uint4 awn;
    if (gp < 15) awn = Wc4[(gp + 1) * 64 + l];

    // conv for next group-pair into the other buffer (overlaps GEMM below)
    if (gp < 15) {
      char* wbuf = ((gp + 1) & 1) ? apk1 : apk0;
      CONV_STEP(gp + 1, wbuf, awn);
    }

    // GEMM for gp from Apk[gp&1]
    const char* rbuf = (gp & 1) ? apk1 : apk0;
#pragma unroll
    for (int par = 0; par < 2; ++par)
#pragma unroll
      for (int K = 0; K < 3; ++K) {
        short8 af[4];
#pragma unroll
        for (int R = 0; R < 4; ++R)
          af[R] = *(const short8*)(rbuf + ((par * 3 + K) * 4 + R) * 1024 +
                                   l * 16);
#pragma unroll
        for (int R = 0; R < 4; ++R) {
          acc[R][0] = __builtin_amdgcn_mfma_f32_16x16x32_bf16(
              af[R], u4s8(Bv[par * 6 + K * 2 + 0]), acc[R][0], 0, 0, 0);
          acc[R][1] = __builtin_amdgcn_mfma_f32_16x16x32_bf16(
              af[R], u4s8(Bv[par * 6 + K * 2 + 1]), acc[R][1], 0, 0, 0);
        }
      }
  }
  __syncthreads();  // all GEMM reads done; LDS reused as S2

  // epilogue: bias + relu -> act LDS (cols 0..63 policy, 64..127 value)
  {
    const int n0 = wv * 32 + lm;
    const int n1 = n0 + 16;
    const float b0 = (n0 < 64) ? pb1[n0] : vb1[n0 - 64];
    const float b1 = (n1 < 64) ? pb1[n1] : vb1[n1 - 64];
#pragma unroll
    for (int R = 0; R < 4; ++R)
#pragma unroll
      for (int r = 0; r < 4; ++r) {
        int row = R * 16 + lq * 4 + r;
        sh.s2.act[row * 132 + n0] = fmaxf(acc[R][0][r] + b0, 0.f);
        sh.s2.act[row * 132 + n1] = fmaxf(acc[R][1][r] + b1, 0.f);
      }
  }
  __syncthreads();

  // layer 2 via MFMA: wave wv owns boards wv*16..+15; 32 neurons x2 heads,
  // K=64; B-fragments pre-packed in Wp2 (piece F, exonerated).
  {
    f32x4 acc2[2][2];  // [head][ntile]
#pragma unroll
    for (int h = 0; h < 2; ++h)
#pragma unroll
      for (int t = 0; t < 2; ++t)
#pragma unroll
        for (int r = 0; r < 4; ++r) acc2[h][t][r] = 0.f;
#pragma unroll
    for (int h = 0; h < 2; ++h) {
#pragma unroll
      for (int k2 = 0; k2 < 2; ++k2) {
        union { u16 s8[8]; short8 v; } afl;
        const float* ap =
            &sh.s2.act[(wv * 16 + lm) * 132 + h * 64 + k2 * 32 + lq * 8];
        f32x4 a0 = *(const f32x4*)ap;
        f32x4 a1 = *(const f32x4*)(ap + 4);
#pragma unroll
        for (int e = 0; e < 4; ++e) {
          afl.s8[e] = f2bf(a0[e]);
          afl.s8[4 + e] = f2bf(a1[e]);
        }
#pragma unroll
        for (int t = 0; t < 2; ++t) {
          uint4 bv = *(const uint4*)&Wp2[
              (size_t)((((h * 2 + k2) * 2 + t) * 64) + lq * 16 + lm) * 8];
          acc2[h][t] = __builtin_amdgcn_mfma_f32_16x16x32_bf16(
              afl.v, u4s8(bv), acc2[h][t], 0, 0, 0);
        }
      }
    }
#pragma unroll
    for (int h = 0; h < 2; ++h)
#pragma unroll
      for (int t = 0; t < 2; ++t) {
        const float bias = (h ? vb2 : pb2)[t * 16 + lm];
#pragma unroll
        for (int r = 0; r < 4; ++r) {
          int board = wv * 16 + lq * 4 + r;
          sh.s2.p2v2[board * 65 + h * 32 + t * 16 + lm] =
              fmaxf(acc2[h][t][r] + bias, 0.f);
        }
      }
  }
  __syncthreads();

  // layer 3 + softmax / tanh: one thread per board (serial, proven)
  if (tid < TB) {
    const float* pv = &sh.s2.p2v2[tid * 65];
    float lg[7];
#pragma unroll
    for (int j = 0; j < 7; ++j) lg[j] = pb3[j];
    for (int n = 0; n < 32; ++n) {
      float t = pv[n];
#pragma unroll
      for (int j = 0; j < 7; ++j) lg[j] = fmaf(t, pw3[n * 7 + j], lg[j]);
    }
    float mx = lg[0];
#pragma unroll
    for (int j = 1; j < 7; ++j) mx = fmaxf(mx, lg[j]);
    float ex[7], ssum = 0.f;
#pragma unroll
    for (int j = 0; j < 7; ++j) {
      ex[j] = expf(lg[j] - mx);
      ssum += ex[j];
    }
    float inv = 1.f / ssum;
    int bg = bid * TB + tid;
#pragma unroll
    for (int j = 0; j < 7; ++j) out[bg * 7 + j] = ex[j] * inv;
    float va = vb3[0];
#pragma unroll
    for (int n = 0; n < 32; ++n) va = fmaf(pv[32 + n], vw3[n], va);
    out[B_TOTAL * 7 + bg] = tanhf(va);
  }
}

// ---------------------------------------------------------------------------
extern "C" void kernel_launch(void* const* d_in, const int* in_sizes, int n_in,
                              void* d_out, int out_size, void* d_ws, size_t ws_size,
                              hipStream_t stream) {
  const float* x     = (const float*)d_in[0];
  const float* convw = (const float*)d_in[1];
  const float* convb = (const float*)d_in[2];
  const float* gamma = (const float*)d_in[3];
  const float* beta  = (const float*)d_in[4];
  const float* pw1 = (const float*)d_in[5];
  const float* pb1 = (const float*)d_in[6];
  const float* pw2 = (const float*)d_in[7];
  const float* pb2 = (const float*)d_in[8];
  const float* pw3 = (const float*)d_in[9];
  const float* pb3 = (const float*)d_in[10];
  const float* vw1 = (const float*)d_in[11];
  const float* vb1 = (const float*)d_in[12];
  const float* vw2 = (const float*)d_in[13];
  const float* vb2 = (const float*)d_in[14];
  const float* vw3 = (const float*)d_in[15];
  const float* vb3 = (const float*)d_in[16];
  float* out = (float*)d_out;

  float* ws   = (float*)d_ws;
  float* sums = ws;                     // 1806 f32
  int*   ctr  = (int*)(ws + 1806);      // 1 int
  float* AD   = ws + 1808;              // 512 f32
  u16*   Wp   = (u16*)(ws + 2320);      // 393216 bf16, 16B-aligned
  u16*   Wp2  = Wp + 393216;            // 4096 bf16
  u16*   Wc   = Wp2 + 4096;             // 8192 bf16

  hipMemsetAsync(ws, 0, 1807 * sizeof(float), stream);
  prep_kernel<<<257, 256, 0, stream>>>(x, pw1, vw1, pw2, vw2, convw, convb,
                                       gamma, beta, Wp, Wp2, Wc, sums, ctr, AD);
  fused_kernel<<<512, 256, 0, stream>>>(x, Wc, AD, Wp, Wp2, pb1, vb1,
                                        pb2, pw3, pb3, vb2, vw3, vb3, out);
}